// Round 7
// baseline (3159.013 us; speedup 1.0000x reference)
//
#include <hip/hip_runtime.h>
#include <hip/hip_bf16.h>
#include <hip/hip_cooperative_groups.h>

namespace cg = cooperative_groups;

// GIN: 2 x (padded-CSR gather-sum + MLP(64->64->64) + BN-stats) + mean pool.
// N=50000, E=800000, H=64, G=16. fp32 in/out.
// R21: single cooperative persistent kernel (1536 blocks x 256 thr, 6/CU via
// launch_bounds(256,6), 18.7 KB LDS). Phases prep -> scatter -> layer0 ->
// layer1 -> norm -> finalize separated by grid.sync(). Gather runs at
// 24 waves/CU (2x R19) because tile size (32 rows) is decoupled from grid
// size (grid-stride). Layer0 writes xb2, never xb (R17 race lesson).
// Fallback: if hipLaunchCooperativeKernel errors, run the proven R19
// 6-dispatch split path.

constexpr int NN = 50000;
constexpr int NE = 800000;
constexpr int HD = 64;
constexpr int NG = 16;
constexpr float BN_EPS = 1e-5f;
constexpr int ROWCAP = 64;    // P(deg>64)~1e-20 at E/N=16
constexpr int NPART = 8;      // XCD partitions (scatter locality)
constexpr int PSZ = 6250;     // rows per partition
constexpr int GRID = 1536;    // 6 blocks/CU x 256 CU
constexpr int TPB = 256;
constexpr int TROWS = 32;                              // rows per MLP tile
constexpr int NTILES = (NN + TROWS - 1) / TROWS;       // 1563
constexpr int SCTV = ((NE + 1023) / 1024) * NPART;     // 6256 virtual chunks
constexpr int NORMV = NN / 16;                         // 3125 virtual blocks

__device__ __forceinline__ int rdl(int v, int l) {
    return __builtin_amdgcn_readlane(v, l);
}

__device__ __forceinline__ int lower_bound_batch(const int* __restrict__ b, int val) {
    int lo = 0, hi = NN;
    while (lo < hi) {
        int mid = (lo + hi) >> 1;
        if (b[mid] < val) lo = mid + 1;
        else hi = mid;
    }
    return lo;
}

// ---------------------------------------------------------------------------
// Fused layer phase (device fn): grid-stride over 32-row tiles.
// Wave w gathers rows [w*8, w*8+8); GEMMs: row = lane&31,
// cols cb = wu*16 + (lane>>5)*8 .. +8 (8 outputs/thread).
// MODE 0: raw gather, write bf16 to xbr. MODE 1: prev-BN+ReLU on the fly.
// ---------------------------------------------------------------------------
template <int MODE>
__device__ __forceinline__ void layer_phase(
    const float* __restrict__ xin, const __hip_bfloat16* __restrict__ xg,
    const int* __restrict__ cnt, const unsigned short* __restrict__ csr,
    const float* __restrict__ stats_prev, const float* __restrict__ gp,
    const float* __restrict__ bep,
    const float* __restrict__ W1, const float* __restrict__ b1,
    const float* __restrict__ W2, const float* __restrict__ b2,
    float* __restrict__ hout, float* __restrict__ stats,
    __hip_bfloat16* __restrict__ xbr,
    float* sh, float* sh2, float (*red)[4][64]) {
    int tid = threadIdx.x;
    int w = tid >> 6, lane = tid & 63;
    int wu = __builtin_amdgcn_readfirstlane(w);
    float sc = 1.f, off = 0.f;
    if (MODE == 1) {
        const float inv = 1.f / (float)NN;
        float mu = stats_prev[lane] * inv;
        float var = stats_prev[64 + lane] * inv - mu * mu;
        sc = gp[lane] * rsqrtf(var + BN_EPS);
        off = bep[lane] - mu * sc;
    }
    int row = lane & 31;
    int cb = wu * 16 + (lane >> 5) * 8;

    for (int t = blockIdx.x; t < NTILES; t += GRID) {
        int base = t * TROWS;
        // ---- gather: wave w fills sh rows [wu*8, wu*8+8) ----
        for (int r = 0; r < 8; r++) {
            int rl = wu * 8 + r;
            int grow = base + rl;
            float acc = 0.f;
            if (grow < NN) {
                int m = min(cnt[grow], ROWCAP);
                int ids = (int)csr[((size_t)grow << 6) + lane];
                float sv = xin[(size_t)grow * HD + lane];
                acc = (MODE == 1) ? fmaxf(fmaf(sv, sc, off), 0.f) : sv;
                int j = 0;
                float a0 = 0.f, a1 = 0.f, a2 = 0.f, a3 = 0.f;
                float a4 = 0.f, a5 = 0.f, a6 = 0.f, a7 = 0.f;
                for (; j + 8 <= m; j += 8) {
                    int n0 = rdl(ids, j);
                    int n1 = rdl(ids, j + 1);
                    int n2 = rdl(ids, j + 2);
                    int n3 = rdl(ids, j + 3);
                    int n4 = rdl(ids, j + 4);
                    int n5 = rdl(ids, j + 5);
                    int n6 = rdl(ids, j + 6);
                    int n7 = rdl(ids, j + 7);
                    float v0 = __bfloat162float(xg[((size_t)n0 << 6) + lane]);
                    float v1 = __bfloat162float(xg[((size_t)n1 << 6) + lane]);
                    float v2 = __bfloat162float(xg[((size_t)n2 << 6) + lane]);
                    float v3 = __bfloat162float(xg[((size_t)n3 << 6) + lane]);
                    float v4 = __bfloat162float(xg[((size_t)n4 << 6) + lane]);
                    float v5 = __bfloat162float(xg[((size_t)n5 << 6) + lane]);
                    float v6 = __bfloat162float(xg[((size_t)n6 << 6) + lane]);
                    float v7 = __bfloat162float(xg[((size_t)n7 << 6) + lane]);
                    if (MODE == 1) {
                        a0 += fmaxf(fmaf(v0, sc, off), 0.f);
                        a1 += fmaxf(fmaf(v1, sc, off), 0.f);
                        a2 += fmaxf(fmaf(v2, sc, off), 0.f);
                        a3 += fmaxf(fmaf(v3, sc, off), 0.f);
                        a4 += fmaxf(fmaf(v4, sc, off), 0.f);
                        a5 += fmaxf(fmaf(v5, sc, off), 0.f);
                        a6 += fmaxf(fmaf(v6, sc, off), 0.f);
                        a7 += fmaxf(fmaf(v7, sc, off), 0.f);
                    } else {
                        a0 += v0; a1 += v1; a2 += v2; a3 += v3;
                        a4 += v4; a5 += v5; a6 += v6; a7 += v7;
                    }
                }
                acc += ((a0 + a1) + (a2 + a3)) + ((a4 + a5) + (a6 + a7));
                for (; j < m; j++) {
                    int nb = rdl(ids, j);
                    float v = __bfloat162float(xg[((size_t)nb << 6) + lane]);
                    acc += (MODE == 1) ? fmaxf(fmaf(v, sc, off), 0.f) : v;
                }
            }
            sh[rl * 65 + lane] = acc;
        }
        __syncthreads();

        // ---- GEMM1: sh -> ReLU -> sh2 ----
        float a8[8];
#pragma unroll
        for (int j = 0; j < 8; j++) a8[j] = b1[cb + j];
        for (int k = 0; k < 64; k++) {
            float a = sh[row * 65 + k];
            float4 w0 = *(const float4*)(W1 + k * 64 + cb);
            float4 w1 = *(const float4*)(W1 + k * 64 + cb + 4);
            a8[0] = fmaf(a, w0.x, a8[0]);
            a8[1] = fmaf(a, w0.y, a8[1]);
            a8[2] = fmaf(a, w0.z, a8[2]);
            a8[3] = fmaf(a, w0.w, a8[3]);
            a8[4] = fmaf(a, w1.x, a8[4]);
            a8[5] = fmaf(a, w1.y, a8[5]);
            a8[6] = fmaf(a, w1.z, a8[6]);
            a8[7] = fmaf(a, w1.w, a8[7]);
        }
#pragma unroll
        for (int j = 0; j < 8; j++)
            sh2[row * 65 + cb + j] = fmaxf(a8[j], 0.f);
        __syncthreads();

        // ---- GEMM2: sh2 -> sh (sh free after GEMM1 barrier) ----
#pragma unroll
        for (int j = 0; j < 8; j++) a8[j] = b2[cb + j];
        for (int k = 0; k < 64; k++) {
            float a = sh2[row * 65 + k];
            float4 w0 = *(const float4*)(W2 + k * 64 + cb);
            float4 w1 = *(const float4*)(W2 + k * 64 + cb + 4);
            a8[0] = fmaf(a, w0.x, a8[0]);
            a8[1] = fmaf(a, w0.y, a8[1]);
            a8[2] = fmaf(a, w0.z, a8[2]);
            a8[3] = fmaf(a, w0.w, a8[3]);
            a8[4] = fmaf(a, w1.x, a8[4]);
            a8[5] = fmaf(a, w1.y, a8[5]);
            a8[6] = fmaf(a, w1.z, a8[6]);
            a8[7] = fmaf(a, w1.w, a8[7]);
        }
#pragma unroll
        for (int j = 0; j < 8; j++)
            sh[row * 65 + cb + j] = a8[j];
        __syncthreads();

        // ---- coalesced stores: fp32 + optional bf16 table ----
#pragma unroll
        for (int i = 0; i < 2; i++) {
            int i4 = tid + 256 * i;
            int rr = i4 >> 4, col = (i4 & 15) * 4;
            int grow = base + rr;
            if (grow < NN) {
                const float* s = sh + rr * 65 + col;
                float4 v = make_float4(s[0], s[1], s[2], s[3]);
                *(float4*)(hout + (size_t)grow * HD + col) = v;
                if (MODE == 0) {
                    union { ushort4 u; __hip_bfloat16 b[4]; } p;
                    p.b[0] = __float2bfloat16(v.x);
                    p.b[1] = __float2bfloat16(v.y);
                    p.b[2] = __float2bfloat16(v.z);
                    p.b[3] = __float2bfloat16(v.w);
                    *(ushort4*)((unsigned short*)xbr + (size_t)grow * HD + col) = p.u;
                }
            }
        }

        // ---- BN-stats partials: wave w sums its 8 rows ----
        {
            float s = 0.f, ss = 0.f;
#pragma unroll
            for (int r = 0; r < 8; r++) {
                int rl = wu * 8 + r;
                float v = (base + rl < NN) ? sh[rl * 65 + lane] : 0.f;
                s += v;
                ss += v * v;
            }
            red[0][wu][lane] = s;
            red[1][wu][lane] = ss;
            __syncthreads();
            if (tid < 64) {
                float S = red[0][0][tid] + red[0][1][tid] + red[0][2][tid] + red[0][3][tid];
                atomicAdd(stats + tid, S);
            } else if (tid < 128) {
                int c = tid - 64;
                float SS = red[1][0][c] + red[1][1][c] + red[1][2][c] + red[1][3][c];
                atomicAdd(stats + 64 + c, SS);
            }
        }
        // next gather write to sh is safe: all sh reads happened before the
        // barrier inside the stats block; red reads (tid<128) don't touch sh.
    }
}

// ---------------------------------------------------------------------------
// The cooperative mega-kernel.
// ---------------------------------------------------------------------------
__global__ __launch_bounds__(256, 6)
void gin_mega(const float* __restrict__ x, const int* __restrict__ ei,
              const int* __restrict__ batch,
              const float* __restrict__ W1_0, const float* __restrict__ b1_0,
              const float* __restrict__ W2_0, const float* __restrict__ b2_0,
              const float* __restrict__ g_0, const float* __restrict__ be_0,
              const float* __restrict__ W1_1, const float* __restrict__ b1_1,
              const float* __restrict__ W2_1, const float* __restrict__ b2_1,
              const float* __restrict__ g_1, const float* __restrict__ be_1,
              float* __restrict__ out, float* __restrict__ stats0,
              float* __restrict__ stats1, float* __restrict__ psums,
              int* __restrict__ cnt, unsigned short* __restrict__ csr,
              __hip_bfloat16* __restrict__ xb, __hip_bfloat16* __restrict__ xb2) {
    cg::grid_group grid = cg::this_grid();
    __shared__ float sh[TROWS * 65];    // 8320 B
    __shared__ float sh2[TROWS * 65];   // 8320 B
    __shared__ float red[2][4][64];     // 2048 B (reused as sg in norm phase)
    int tid = threadIdx.x;
    int bid = blockIdx.x;

    // ================= phase 0: prep (bf16 table + zeroing) =================
    for (int i4 = bid * TPB + tid; i4 < NN * HD / 4; i4 += GRID * TPB) {
        if (i4 < NN) cnt[i4] = 0;
        float4 v = *(const float4*)(x + (size_t)i4 * 4);
        union { ushort4 u; __hip_bfloat16 b[4]; } p;
        p.b[0] = __float2bfloat16(v.x);
        p.b[1] = __float2bfloat16(v.y);
        p.b[2] = __float2bfloat16(v.z);
        p.b[3] = __float2bfloat16(v.w);
        *(ushort4*)((unsigned short*)xb + (size_t)i4 * 4) = p.u;
    }
    if (bid == 0) {
        if (tid < 128) stats0[tid] = 0.f;
        else stats1[tid - 128] = 0.f;
    } else if (bid == 1) {
        *(float4*)(psums + tid * 4) = make_float4(0.f, 0.f, 0.f, 0.f);
    }
    grid.sync();

    // ================= phase 1: XCD-partitioned scatter =====================
    // v & 7 constant per block (GRID % 8 == 0) -> stable partition->XCD affinity.
    for (int v = bid; v < SCTV; v += GRID) {
        int p = v & 7;
        int chunk = v >> 3;
        int e4 = (chunk * 256 + tid) * 4;
        if (e4 < NE) {
            int4 s = *(const int4*)(ei + e4);
            int4 d = *(const int4*)(ei + NE + e4);
            int lo = p * PSZ, hi = lo + PSZ;
            int slot;
            if (d.x >= lo && d.x < hi) {
                slot = atomicAdd(&cnt[d.x], 1);
                if (slot < ROWCAP) csr[(d.x << 6) + slot] = (unsigned short)s.x;
            }
            if (d.y >= lo && d.y < hi) {
                slot = atomicAdd(&cnt[d.y], 1);
                if (slot < ROWCAP) csr[(d.y << 6) + slot] = (unsigned short)s.y;
            }
            if (d.z >= lo && d.z < hi) {
                slot = atomicAdd(&cnt[d.z], 1);
                if (slot < ROWCAP) csr[(d.z << 6) + slot] = (unsigned short)s.z;
            }
            if (d.w >= lo && d.w < hi) {
                slot = atomicAdd(&cnt[d.w], 1);
                if (slot < ROWCAP) csr[(d.w << 6) + slot] = (unsigned short)s.w;
            }
        }
    }
    grid.sync();

    // ================= phase 2: layer 0 (gather + MLP + stats0) =============
    layer_phase<0>(x, xb, cnt, csr, nullptr, nullptr, nullptr,
                   W1_0, b1_0, W2_0, b2_0, out, stats0, xb2, sh, sh2, red);
    grid.sync();

    // ================= phase 3: layer 1 (BN0+ReLU on the fly) ===============
    layer_phase<1>(out, xb2, cnt, csr, stats0, g_0, be_0,
                   W1_1, b1_1, W2_1, b2_1, out, stats1, (__hip_bfloat16*)nullptr,
                   sh, sh2, red);
    grid.sync();

    // ================= phase 4: final BN + ReLU + pool partials =============
    {
        float* sg = &red[0][0][0];  // 128 floats
        for (int nb = bid; nb < NORMV; nb += GRID) {
            if (tid < 128) sg[tid] = 0.f;
            __syncthreads();
            size_t i4 = (size_t)nb * 256 + tid;
            int rrow = (int)(i4 >> 4);
            int base_row = nb * 16;
            int g0 = batch[base_row];
            size_t off = i4 * 4;
            int col = (int)(off & 63);
            float4 v = *(const float4*)(out + off);
            float4 sm = *(const float4*)(stats1 + col);
            float4 sq = *(const float4*)(stats1 + 64 + col);
            float4 gg = *(const float4*)(g_1 + col);
            float4 bb = *(const float4*)(be_1 + col);
            const float inv = 1.f / (float)NN;
            float4 o;
            {
                float mu = sm.x * inv, var = sq.x * inv - mu * mu;
                float s = gg.x * rsqrtf(var + BN_EPS);
                o.x = fmaxf((v.x - mu) * s + bb.x, 0.f);
            }
            {
                float mu = sm.y * inv, var = sq.y * inv - mu * mu;
                float s = gg.y * rsqrtf(var + BN_EPS);
                o.y = fmaxf((v.y - mu) * s + bb.y, 0.f);
            }
            {
                float mu = sm.z * inv, var = sq.z * inv - mu * mu;
                float s = gg.z * rsqrtf(var + BN_EPS);
                o.z = fmaxf((v.z - mu) * s + bb.z, 0.f);
            }
            {
                float mu = sm.w * inv, var = sq.w * inv - mu * mu;
                float s = gg.w * rsqrtf(var + BN_EPS);
                o.w = fmaxf((v.w - mu) * s + bb.w, 0.f);
            }
            *(float4*)(out + off) = o;

            int dg = batch[rrow] - g0;
            if (dg <= 1) {
                atomicAdd(&sg[dg * 64 + col + 0], o.x);
                atomicAdd(&sg[dg * 64 + col + 1], o.y);
                atomicAdd(&sg[dg * 64 + col + 2], o.z);
                atomicAdd(&sg[dg * 64 + col + 3], o.w);
            } else {
                int gid = g0 + dg;
                atomicAdd(&psums[gid * HD + col + 0], o.x);
                atomicAdd(&psums[gid * HD + col + 1], o.y);
                atomicAdd(&psums[gid * HD + col + 2], o.z);
                atomicAdd(&psums[gid * HD + col + 3], o.w);
            }
            __syncthreads();
            if (tid < 128) {
                int d = tid >> 6;
                int c = tid & 63;
                float s = sg[d * 64 + c];
                if (g0 + d < NG && s != 0.f) atomicAdd(&psums[(g0 + d) * HD + c], s);
            }
        }
    }
    grid.sync();

    // ================= phase 5: pool finalize (block 0) =====================
    if (bid == 0) {
        for (int idx = tid; idx < NG * HD; idx += TPB) {
            int g = idx >> 6;
            int col = idx & 63;
            int s = lower_bound_batch(batch, g);
            int e = lower_bound_batch(batch, g + 1);
            float c = (float)(e - s);
            out[(size_t)NN * HD + g * HD + col] = psums[g * HD + col] / fmaxf(c, 1.f);
        }
    }
}

// ===========================================================================
// Fallback path (R19, measured 278 us): used only if cooperative launch fails.
// ===========================================================================
__global__ __launch_bounds__(256)
void prep_kernel(const float* __restrict__ x, __hip_bfloat16* __restrict__ xb,
                 int* __restrict__ cnt, float* __restrict__ stats0,
                 float* __restrict__ stats1, float* __restrict__ psums) {
    int i4 = blockIdx.x * 256 + threadIdx.x;
    if (i4 < NN) cnt[i4] = 0;
    if (blockIdx.x == 0) {
        if (threadIdx.x < 128) stats0[threadIdx.x] = 0.f;
        else stats1[threadIdx.x - 128] = 0.f;
    } else if (blockIdx.x == 1) {
        *(float4*)(psums + threadIdx.x * 4) = make_float4(0.f, 0.f, 0.f, 0.f);
    }
    if (i4 >= NN * HD / 4) return;
    float4 v = *(const float4*)(x + (size_t)i4 * 4);
    union { ushort4 u; __hip_bfloat16 b[4]; } p;
    p.b[0] = __float2bfloat16(v.x);
    p.b[1] = __float2bfloat16(v.y);
    p.b[2] = __float2bfloat16(v.z);
    p.b[3] = __float2bfloat16(v.w);
    *(ushort4*)((unsigned short*)xb + (size_t)i4 * 4) = p.u;
}

__global__ __launch_bounds__(256)
void scatter_kernel(const int* __restrict__ ei, int* __restrict__ cnt,
                    unsigned short* __restrict__ csr) {
    int p = blockIdx.x & 7;
    int chunk = blockIdx.x >> 3;
    int e4 = (chunk * 256 + threadIdx.x) * 4;
    if (e4 >= NE) return;
    int4 s = *(const int4*)(ei + e4);
    int4 d = *(const int4*)(ei + NE + e4);
    int lo = p * PSZ, hi = lo + PSZ;
    int slot;
    if (d.x >= lo && d.x < hi) {
        slot = atomicAdd(&cnt[d.x], 1);
        if (slot < ROWCAP) csr[(d.x << 6) + slot] = (unsigned short)s.x;
    }
    if (d.y >= lo && d.y < hi) {
        slot = atomicAdd(&cnt[d.y], 1);
        if (slot < ROWCAP) csr[(d.y << 6) + slot] = (unsigned short)s.y;
    }
    if (d.z >= lo && d.z < hi) {
        slot = atomicAdd(&cnt[d.z], 1);
        if (slot < ROWCAP) csr[(d.z << 6) + slot] = (unsigned short)s.z;
    }
    if (d.w >= lo && d.w < hi) {
        slot = atomicAdd(&cnt[d.w], 1);
        if (slot < ROWCAP) csr[(d.w << 6) + slot] = (unsigned short)s.w;
    }
}

template <int MODE>
__global__ __launch_bounds__(512)
void layer_kernel(const float* __restrict__ xin, const __hip_bfloat16* __restrict__ xg,
                  const int* __restrict__ cnt, const unsigned short* __restrict__ csr,
                  const float* __restrict__ stats_prev, const float* __restrict__ gp,
                  const float* __restrict__ bep,
                  const float* __restrict__ W1, const float* __restrict__ b1,
                  const float* __restrict__ W2, const float* __restrict__ b2,
                  float* __restrict__ hout, float* __restrict__ stats,
                  __hip_bfloat16* __restrict__ xbr) {
    __shared__ float sh[128 * 65];
    __shared__ float red[2][8][64];
    int tid = threadIdx.x;
    int base = blockIdx.x * 128;
    int w = tid >> 6, lane = tid & 63;
    int wu = __builtin_amdgcn_readfirstlane(w);

    float sc = 1.f, off = 0.f;
    if (MODE == 1) {
        const float inv = 1.f / (float)NN;
        float mu = stats_prev[lane] * inv;
        float var = stats_prev[64 + lane] * inv - mu * mu;
        sc = gp[lane] * rsqrtf(var + BN_EPS);
        off = bep[lane] - mu * sc;
    }

    for (int rl = wu * 16; rl < wu * 16 + 16; rl++) {
        int grow = base + rl;
        float acc = 0.f;
        if (grow < NN) {
            int m = min(cnt[grow], ROWCAP);
            int ids = (int)csr[((size_t)grow << 6) + lane];
            float sv = xin[(size_t)grow * HD + lane];
            acc = (MODE == 1) ? fmaxf(fmaf(sv, sc, off), 0.f) : sv;
            int j = 0;
            float a0 = 0.f, a1 = 0.f, a2 = 0.f, a3 = 0.f;
            float a4 = 0.f, a5 = 0.f, a6 = 0.f, a7 = 0.f;
            for (; j + 8 <= m; j += 8) {
                int n0 = rdl(ids, j);
                int n1 = rdl(ids, j + 1);
                int n2 = rdl(ids, j + 2);
                int n3 = rdl(ids, j + 3);
                int n4 = rdl(ids, j + 4);
                int n5 = rdl(ids, j + 5);
                int n6 = rdl(ids, j + 6);
                int n7 = rdl(ids, j + 7);
                float v0 = __bfloat162float(xg[((size_t)n0 << 6) + lane]);
                float v1 = __bfloat162float(xg[((size_t)n1 << 6) + lane]);
                float v2 = __bfloat162float(xg[((size_t)n2 << 6) + lane]);
                float v3 = __bfloat162float(xg[((size_t)n3 << 6) + lane]);
                float v4 = __bfloat162float(xg[((size_t)n4 << 6) + lane]);
                float v5 = __bfloat162float(xg[((size_t)n5 << 6) + lane]);
                float v6 = __bfloat162float(xg[((size_t)n6 << 6) + lane]);
                float v7 = __bfloat162float(xg[((size_t)n7 << 6) + lane]);
                if (MODE == 1) {
                    a0 += fmaxf(fmaf(v0, sc, off), 0.f);
                    a1 += fmaxf(fmaf(v1, sc, off), 0.f);
                    a2 += fmaxf(fmaf(v2, sc, off), 0.f);
                    a3 += fmaxf(fmaf(v3, sc, off), 0.f);
                    a4 += fmaxf(fmaf(v4, sc, off), 0.f);
                    a5 += fmaxf(fmaf(v5, sc, off), 0.f);
                    a6 += fmaxf(fmaf(v6, sc, off), 0.f);
                    a7 += fmaxf(fmaf(v7, sc, off), 0.f);
                } else {
                    a0 += v0; a1 += v1; a2 += v2; a3 += v3;
                    a4 += v4; a5 += v5; a6 += v6; a7 += v7;
                }
            }
            acc += ((a0 + a1) + (a2 + a3)) + ((a4 + a5) + (a6 + a7));
            for (; j < m; j++) {
                int nb = rdl(ids, j);
                float v = __bfloat162float(xg[((size_t)nb << 6) + lane]);
                acc += (MODE == 1) ? fmaxf(fmaf(v, sc, off), 0.f) : v;
            }
        }
        sh[rl * 65 + lane] = acc;
    }
    __syncthreads();

    float acc0[8], acc1[8];
#pragma unroll
    for (int j = 0; j < 8; j++) { acc0[j] = b1[wu * 8 + j]; acc1[j] = acc0[j]; }
    for (int k = 0; k < 64; k++) {
        float a0 = sh[lane * 65 + k];
        float a1 = sh[(64 + lane) * 65 + k];
        const float4* wr = (const float4*)(W1 + k * 64 + wu * 8);
#pragma unroll
        for (int q = 0; q < 2; q++) {
            float4 wv = wr[q];
            acc0[4 * q + 0] = fmaf(a0, wv.x, acc0[4 * q + 0]);
            acc0[4 * q + 1] = fmaf(a0, wv.y, acc0[4 * q + 1]);
            acc0[4 * q + 2] = fmaf(a0, wv.z, acc0[4 * q + 2]);
            acc0[4 * q + 3] = fmaf(a0, wv.w, acc0[4 * q + 3]);
            acc1[4 * q + 0] = fmaf(a1, wv.x, acc1[4 * q + 0]);
            acc1[4 * q + 1] = fmaf(a1, wv.y, acc1[4 * q + 1]);
            acc1[4 * q + 2] = fmaf(a1, wv.z, acc1[4 * q + 2]);
            acc1[4 * q + 3] = fmaf(a1, wv.w, acc1[4 * q + 3]);
        }
    }
    __syncthreads();
#pragma unroll
    for (int j = 0; j < 8; j++) {
        sh[lane * 65 + wu * 8 + j] = fmaxf(acc0[j], 0.f);
        sh[(64 + lane) * 65 + wu * 8 + j] = fmaxf(acc1[j], 0.f);
    }
    __syncthreads();
#pragma unroll
    for (int j = 0; j < 8; j++) { acc0[j] = b2[wu * 8 + j]; acc1[j] = acc0[j]; }
    for (int k = 0; k < 64; k++) {
        float a0 = sh[lane * 65 + k];
        float a1 = sh[(64 + lane) * 65 + k];
        const float4* wr = (const float4*)(W2 + k * 64 + wu * 8);
#pragma unroll
        for (int q = 0; q < 2; q++) {
            float4 wv = wr[q];
            acc0[4 * q + 0] = fmaf(a0, wv.x, acc0[4 * q + 0]);
            acc0[4 * q + 1] = fmaf(a0, wv.y, acc0[4 * q + 1]);
            acc0[4 * q + 2] = fmaf(a0, wv.z, acc0[4 * q + 2]);
            acc0[4 * q + 3] = fmaf(a0, wv.w, acc0[4 * q + 3]);
            acc1[4 * q + 0] = fmaf(a1, wv.x, acc1[4 * q + 0]);
            acc1[4 * q + 1] = fmaf(a1, wv.y, acc1[4 * q + 1]);
            acc1[4 * q + 2] = fmaf(a1, wv.z, acc1[4 * q + 2]);
            acc1[4 * q + 3] = fmaf(a1, wv.w, acc1[4 * q + 3]);
        }
    }
    __syncthreads();
#pragma unroll
    for (int j = 0; j < 8; j++) {
        sh[lane * 65 + wu * 8 + j] = acc0[j];
        sh[(64 + lane) * 65 + wu * 8 + j] = acc1[j];
    }
    __syncthreads();
#pragma unroll
    for (int i = 0; i < 4; i++) {
        int i4 = tid + 512 * i;
        int row = i4 >> 4, col = (i4 & 15) * 4;
        int grow = base + row;
        if (grow < NN) {
            const float* s = sh + row * 65 + col;
            float4 v = make_float4(s[0], s[1], s[2], s[3]);
            *(float4*)(hout + (size_t)grow * HD + col) = v;
            if (xbr) {
                union { ushort4 u; __hip_bfloat16 b[4]; } p;
                p.b[0] = __float2bfloat16(v.x);
                p.b[1] = __float2bfloat16(v.y);
                p.b[2] = __float2bfloat16(v.z);
                p.b[3] = __float2bfloat16(v.w);
                *(ushort4*)((unsigned short*)xbr + (size_t)grow * HD + col) = p.u;
            }
        }
    }
    {
        float s = 0.f, ss = 0.f;
#pragma unroll
        for (int r = 0; r < 16; r++) {
            int rl = wu * 16 + r;
            float v = (base + rl < NN) ? sh[rl * 65 + lane] : 0.f;
            s += v;
            ss += v * v;
        }
        red[0][wu][lane] = s;
        red[1][wu][lane] = ss;
        __syncthreads();
        if (tid < 64) {
            float S = 0.f;
#pragma unroll
            for (int q = 0; q < 8; q++) S += red[0][q][tid];
            atomicAdd(stats + tid, S);
        } else if (tid < 128) {
            int c = tid - 64;
            float SS = 0.f;
#pragma unroll
            for (int q = 0; q < 8; q++) SS += red[1][q][c];
            atomicAdd(stats + 64 + c, SS);
        }
    }
}

__global__ __launch_bounds__(256)
void norm_kernel(float* h, const float* __restrict__ stats,
                 const float* __restrict__ g, const float* __restrict__ be,
                 const int* __restrict__ batch, float* __restrict__ psums) {
    __shared__ float sg[2][64];
    if (threadIdx.x < 128) sg[threadIdx.x >> 6][threadIdx.x & 63] = 0.f;
    __syncthreads();
    size_t i4 = (size_t)blockIdx.x * 256 + threadIdx.x;
    int row = (int)(i4 >> 4);
    int base_row = blockIdx.x * 16;
    int g0 = batch[base_row];
    size_t off = i4 * 4;
    int col = (int)(off & 63);
    float4 v = *(const float4*)(h + off);
    float4 sm = *(const float4*)(stats + col);
    float4 sq = *(const float4*)(stats + 64 + col);
    float4 gg = *(const float4*)(g + col);
    float4 bb = *(const float4*)(be + col);
    const float inv = 1.f / (float)NN;
    float4 o;
    {
        float mu = sm.x * inv, var = sq.x * inv - mu * mu;
        float sc = gg.x * rsqrtf(var + BN_EPS);
        o.x = fmaxf((v.x - mu) * sc + bb.x, 0.f);
    }
    {
        float mu = sm.y * inv, var = sq.y * inv - mu * mu;
        float sc = gg.y * rsqrtf(var + BN_EPS);
        o.y = fmaxf((v.y - mu) * sc + bb.y, 0.f);
    }
    {
        float mu = sm.z * inv, var = sq.z * inv - mu * mu;
        float sc = gg.z * rsqrtf(var + BN_EPS);
        o.z = fmaxf((v.z - mu) * sc + bb.z, 0.f);
    }
    {
        float mu = sm.w * inv, var = sq.w * inv - mu * mu;
        float sc = gg.w * rsqrtf(var + BN_EPS);
        o.w = fmaxf((v.w - mu) * sc + bb.w, 0.f);
    }
    *(float4*)(h + off) = o;
    int dg = batch[row] - g0;
    if (dg <= 1) {
        atomicAdd(&sg[dg][col + 0], o.x);
        atomicAdd(&sg[dg][col + 1], o.y);
        atomicAdd(&sg[dg][col + 2], o.z);
        atomicAdd(&sg[dg][col + 3], o.w);
    } else {
        int gid = g0 + dg;
        atomicAdd(&psums[gid * HD + col + 0], o.x);
        atomicAdd(&psums[gid * HD + col + 1], o.y);
        atomicAdd(&psums[gid * HD + col + 2], o.z);
        atomicAdd(&psums[gid * HD + col + 3], o.w);
    }
    __syncthreads();
    if (threadIdx.x < 128) {
        int d = threadIdx.x >> 6;
        int c = threadIdx.x & 63;
        float s = sg[d][c];
        if (g0 + d < NG && s != 0.f) atomicAdd(&psums[(g0 + d) * HD + c], s);
    }
}

__global__ __launch_bounds__(1024)
void pool_finalize_kernel(const float* __restrict__ sums, const int* __restrict__ batch,
                          float* __restrict__ out) {
    int g = threadIdx.x >> 6;
    int col = threadIdx.x & 63;
    int s = lower_bound_batch(batch, g);
    int e = lower_bound_batch(batch, g + 1);
    float cnt = (float)(e - s);
    out[g * HD + col] = sums[g * HD + col] / fmaxf(cnt, 1.f);
}

extern "C" void kernel_launch(void* const* d_in, const int* in_sizes, int n_in,
                              void* d_out, int out_size, void* d_ws, size_t ws_size,
                              hipStream_t stream) {
    const float* x = (const float*)d_in[0];
    const int* ei = (const int*)d_in[1];
    const int* batch = (const int*)d_in[2];
    const float* W1_0 = (const float*)d_in[3];
    const float* b1_0 = (const float*)d_in[4];
    const float* W2_0 = (const float*)d_in[5];
    const float* b2_0 = (const float*)d_in[6];
    const float* g_0 = (const float*)d_in[7];
    const float* be_0 = (const float*)d_in[8];
    const float* W1_1 = (const float*)d_in[9];
    const float* b1_1 = (const float*)d_in[10];
    const float* W2_1 = (const float*)d_in[11];
    const float* b2_1 = (const float*)d_in[12];
    const float* g_1 = (const float*)d_in[13];
    const float* be_1 = (const float*)d_in[14];

    float* out = (float*)d_out;

    // workspace layout (~20 MB)
    float* stats0 = (float*)d_ws;                      // 128 f32
    float* stats1 = stats0 + 128;                      // 128 f32
    float* psums = stats1 + 128;                       // 1024 f32
    int* cnt = (int*)(psums + 1024);                   // NN int
    unsigned short* csr = (unsigned short*)(cnt + NN); // NN*ROWCAP u16 (6.4 MB)
    __hip_bfloat16* xb = (__hip_bfloat16*)(csr + (size_t)NN * ROWCAP);   // bf16 x
    __hip_bfloat16* xb2 = xb + (size_t)NN * HD;        // bf16 raw L0 (separate!)

    // ---- cooperative mega-kernel ----
    void* args[] = {
        (void*)&x, (void*)&ei, (void*)&batch,
        (void*)&W1_0, (void*)&b1_0, (void*)&W2_0, (void*)&b2_0,
        (void*)&g_0, (void*)&be_0,
        (void*)&W1_1, (void*)&b1_1, (void*)&W2_1, (void*)&b2_1,
        (void*)&g_1, (void*)&be_1,
        (void*)&out, (void*)&stats0, (void*)&stats1, (void*)&psums,
        (void*)&cnt, (void*)&csr, (void*)&xb, (void*)&xb2};
    hipError_t err = hipLaunchCooperativeKernel((const void*)gin_mega,
                                                dim3(GRID), dim3(TPB),
                                                args, 0, stream);
    if (err == hipSuccess) return;

    // ---- fallback: proven R19 6-dispatch split path ----
    (void)hipGetLastError();  // clear error state
    dim3 b256(256);
    dim3 b512(512);
    int layer_grid = (NN + 127) / 128;            // 391
    int norm_grid = (NN * HD / 4 + 255) / 256;    // 3125
    int sct_grid = ((NE + 1023) / 1024) * NPART;  // 6256

    prep_kernel<<<norm_grid, b256, 0, stream>>>(x, xb, cnt, stats0, stats1, psums);
    scatter_kernel<<<sct_grid, b256, 0, stream>>>(ei, cnt, csr);
    layer_kernel<0><<<layer_grid, b512, 0, stream>>>(
        x, xb, cnt, csr, nullptr, nullptr, nullptr,
        W1_0, b1_0, W2_0, b2_0, out, stats0, xb2);
    layer_kernel<1><<<layer_grid, b512, 0, stream>>>(
        out, xb2, cnt, csr, stats0, g_0, be_0,
        W1_1, b1_1, W2_1, b2_1, out, stats1, (__hip_bfloat16*)nullptr);
    norm_kernel<<<norm_grid, b256, 0, stream>>>(out, stats1, g_1, be_1, batch, psums);
    pool_finalize_kernel<<<1, dim3(1024), 0, stream>>>(psums, batch, out + (size_t)NN * HD);
}

// Round 8
// 1063.079 us; speedup vs baseline: 2.9716x; 2.9716x over previous
//
#include <hip/hip_runtime.h>
#include <hip/hip_bf16.h>

// GIN: 2 x (padded-CSR gather-sum + MLP(64->64->64) + BN-stats) + mean pool.
// N=50000, E=800000, H=64, G=16. fp32 in/out.
// R22: persistent mega-kernel (regular launch, 1536 blocks x 256thr; residency
// proven by R21's 73% occupancy) with a CUSTOM device barrier replacing
// grid.sync() (which burned 5.8 GB of cache-invalidate spin traffic, 3.1 ms):
//   arrive: one atomic fetch_add(RELEASE, AGENT) per block (L2 writeback,
//           needed anyway to publish phase outputs cross-XCD)
//   wait:   thread 0 only, RELAXED agent polls + s_sleep(8) (no invalidate
//           per poll), one ACQUIRE load on exit.
// Phases re-balanced vs R21: gather (per-wave row stride, XCD-affine) and MLP
// (64-row tiles, 782 tiles ~ 3/CU) are separate phases via buf_h.
// 2 dispatches: prep (zeroes ctr/cnt/stats/psums + bf16 table), mega.

constexpr int NN = 50000;
constexpr int NE = 800000;
constexpr int HD = 64;
constexpr int NG = 16;
constexpr float BN_EPS = 1e-5f;
constexpr int ROWCAP = 64;    // P(deg>64)~1e-20 at E/N=16
constexpr int NPART = 8;      // XCD partitions
constexpr int PSZ = 6250;     // rows per partition
constexpr int GRID = 1536;    // 6 blocks/CU x 256 CU (R21-proven resident)
constexpr int TPB = 256;
constexpr int SCTV = ((NE + 1023) / 1024) * NPART;   // 6256 scatter chunks
constexpr int MTILES = (NN + 63) / 64;               // 782 MLP tiles
constexpr int NORMV = NN / 16;                       // 3125 norm chunks
constexpr int WPP = (GRID / NPART) * 4;              // 768 waves per partition

__device__ __forceinline__ int rdl(int v, int l) {
    return __builtin_amdgcn_readlane(v, l);
}

// ---------------------------------------------------------------------------
// Low-traffic device barrier. All GRID blocks must call it.
// ---------------------------------------------------------------------------
__device__ __forceinline__ void devbar(unsigned int* ctr, unsigned int target) {
    __syncthreads();
    if (threadIdx.x == 0) {
        __hip_atomic_fetch_add(ctr, 1u, __ATOMIC_RELEASE, __HIP_MEMORY_SCOPE_AGENT);
        while (__hip_atomic_load(ctr, __ATOMIC_RELAXED, __HIP_MEMORY_SCOPE_AGENT) < target)
            __builtin_amdgcn_s_sleep(8);
        (void)__hip_atomic_load(ctr, __ATOMIC_ACQUIRE, __HIP_MEMORY_SCOPE_AGENT);
    }
    __syncthreads();
}

__device__ __forceinline__ int lower_bound_batch(const int* __restrict__ b, int val) {
    int lo = 0, hi = NN;
    while (lo < hi) {
        int mid = (lo + hi) >> 1;
        if (b[mid] < val) lo = mid + 1;
        else hi = mid;
    }
    return lo;
}

// ---------------------------------------------------------------------------
// Prep dispatch: bf16 table; zero cnt, stats0/1, psums, barrier ctr.
// ---------------------------------------------------------------------------
__global__ __launch_bounds__(256)
void prep_kernel(const float* __restrict__ x, __hip_bfloat16* __restrict__ xb,
                 int* __restrict__ cnt, float* __restrict__ stats0,
                 float* __restrict__ stats1, float* __restrict__ psums,
                 unsigned int* __restrict__ ctr) {
    int i4 = blockIdx.x * 256 + threadIdx.x;
    if (i4 < NN) cnt[i4] = 0;
    if (blockIdx.x == 0) {
        if (threadIdx.x < 128) stats0[threadIdx.x] = 0.f;
        else stats1[threadIdx.x - 128] = 0.f;
    } else if (blockIdx.x == 1) {
        *(float4*)(psums + threadIdx.x * 4) = make_float4(0.f, 0.f, 0.f, 0.f);
    } else if (blockIdx.x == 2 && threadIdx.x == 0) {
        *ctr = 0u;
    }
    if (i4 >= NN * HD / 4) return;
    float4 v = *(const float4*)(x + (size_t)i4 * 4);
    union { ushort4 u; __hip_bfloat16 b[4]; } p;
    p.b[0] = __float2bfloat16(v.x);
    p.b[1] = __float2bfloat16(v.y);
    p.b[2] = __float2bfloat16(v.z);
    p.b[3] = __float2bfloat16(v.w);
    *(ushort4*)((unsigned short*)xb + (size_t)i4 * 4) = p.u;
}

// ---------------------------------------------------------------------------
// Gather phase: per-wave grid-stride over rows, XCD-affine (partition = bid&7,
// matching the scatter partition so csr/cnt lines are read on the XCD that
// wrote them). MODE 0: raw sum of bf16 rows + fp32 self term.
// MODE 1: apply prev-layer BN+ReLU to self term and gathered values.
// Output: buf_h[row][lane] fp32.
// ---------------------------------------------------------------------------
template <int MODE>
__device__ void gather_phase(const float* __restrict__ xin,
                             const __hip_bfloat16* __restrict__ xg,
                             const int* __restrict__ cnt,
                             const unsigned short* __restrict__ csr,
                             const float* __restrict__ stats_prev,
                             const float* __restrict__ gp,
                             const float* __restrict__ bep,
                             float* __restrict__ bh) {
    int w = threadIdx.x >> 6, lane = threadIdx.x & 63;
    int p = blockIdx.x & 7;
    int wg = (blockIdx.x >> 3) * 4 + w;   // 0..767 within partition
    float sc = 1.f, off = 0.f;
    if (MODE == 1) {
        const float inv = 1.f / (float)NN;
        float mu = stats_prev[lane] * inv;
        float var = stats_prev[64 + lane] * inv - mu * mu;
        sc = gp[lane] * rsqrtf(var + BN_EPS);
        off = bep[lane] - mu * sc;
    }
    int rend = (p + 1) * PSZ;
    for (int r = p * PSZ + wg; r < rend; r += WPP) {
        int m = min(cnt[r], ROWCAP);
        int ids = (int)csr[((size_t)r << 6) + lane];
        float sv = xin[(size_t)r * HD + lane];
        float acc = (MODE == 1) ? fmaxf(fmaf(sv, sc, off), 0.f) : sv;
        int j = 0;
        float a0 = 0.f, a1 = 0.f, a2 = 0.f, a3 = 0.f;
        float a4 = 0.f, a5 = 0.f, a6 = 0.f, a7 = 0.f;
        for (; j + 8 <= m; j += 8) {
            int n0 = rdl(ids, j);
            int n1 = rdl(ids, j + 1);
            int n2 = rdl(ids, j + 2);
            int n3 = rdl(ids, j + 3);
            int n4 = rdl(ids, j + 4);
            int n5 = rdl(ids, j + 5);
            int n6 = rdl(ids, j + 6);
            int n7 = rdl(ids, j + 7);
            float v0 = __bfloat162float(xg[((size_t)n0 << 6) + lane]);
            float v1 = __bfloat162float(xg[((size_t)n1 << 6) + lane]);
            float v2 = __bfloat162float(xg[((size_t)n2 << 6) + lane]);
            float v3 = __bfloat162float(xg[((size_t)n3 << 6) + lane]);
            float v4 = __bfloat162float(xg[((size_t)n4 << 6) + lane]);
            float v5 = __bfloat162float(xg[((size_t)n5 << 6) + lane]);
            float v6 = __bfloat162float(xg[((size_t)n6 << 6) + lane]);
            float v7 = __bfloat162float(xg[((size_t)n7 << 6) + lane]);
            if (MODE == 1) {
                a0 += fmaxf(fmaf(v0, sc, off), 0.f);
                a1 += fmaxf(fmaf(v1, sc, off), 0.f);
                a2 += fmaxf(fmaf(v2, sc, off), 0.f);
                a3 += fmaxf(fmaf(v3, sc, off), 0.f);
                a4 += fmaxf(fmaf(v4, sc, off), 0.f);
                a5 += fmaxf(fmaf(v5, sc, off), 0.f);
                a6 += fmaxf(fmaf(v6, sc, off), 0.f);
                a7 += fmaxf(fmaf(v7, sc, off), 0.f);
            } else {
                a0 += v0; a1 += v1; a2 += v2; a3 += v3;
                a4 += v4; a5 += v5; a6 += v6; a7 += v7;
            }
        }
        acc += ((a0 + a1) + (a2 + a3)) + ((a4 + a5) + (a6 + a7));
        for (; j < m; j++) {
            int nb = rdl(ids, j);
            float v = __bfloat162float(xg[((size_t)nb << 6) + lane]);
            acc += (MODE == 1) ? fmaxf(fmaf(v, sc, off), 0.f) : v;
        }
        bh[(size_t)r * HD + lane] = acc;
    }
}

// ---------------------------------------------------------------------------
// MLP phase: 64-row tiles (782 tiles, ~3/CU). lane = row source within half,
// wave-uniform cb = wu*16 -> scalar W loads. In-place ReLU (R19-proven flow).
// WRITE_XB: also emit bf16 raw table (layer 0 only).
// ---------------------------------------------------------------------------
template <bool WRITE_XB>
__device__ void mlp_phase(const float* __restrict__ bh,
                          const float* __restrict__ W1, const float* __restrict__ b1,
                          const float* __restrict__ W2, const float* __restrict__ b2,
                          float* __restrict__ hout, float* __restrict__ stats,
                          __hip_bfloat16* __restrict__ xbr,
                          float* sh, float (*red)[4][64]) {
    int tid = threadIdx.x;
    int w = tid >> 6, lane = tid & 63;
    int wu = __builtin_amdgcn_readfirstlane(w);
    int cb = wu * 16;

    for (int t = blockIdx.x; t < MTILES; t += GRID) {
        int base = t * 64;
        // ---- stage 64x64 tile ----
#pragma unroll
        for (int i = 0; i < 4; i++) {
            int i4 = tid + 256 * i;
            int row = i4 >> 4, col = (i4 & 15) * 4;
            int grow = base + row;
            float4 v = (grow < NN) ? *(const float4*)(bh + (size_t)grow * HD + col)
                                   : make_float4(0.f, 0.f, 0.f, 0.f);
            float* d = sh + row * 65 + col;
            d[0] = v.x; d[1] = v.y; d[2] = v.z; d[3] = v.w;
        }
        __syncthreads();

        // ---- GEMM1: row = lane, cols cb..cb+16 ----
        float acc[16];
#pragma unroll
        for (int j = 0; j < 16; j++) acc[j] = b1[cb + j];
        for (int k = 0; k < 64; k++) {
            float a = sh[lane * 65 + k];
            const float4* wr = (const float4*)(W1 + k * 64 + cb);
#pragma unroll
            for (int q = 0; q < 4; q++) {
                float4 wv = wr[q];
                acc[4 * q + 0] = fmaf(a, wv.x, acc[4 * q + 0]);
                acc[4 * q + 1] = fmaf(a, wv.y, acc[4 * q + 1]);
                acc[4 * q + 2] = fmaf(a, wv.z, acc[4 * q + 2]);
                acc[4 * q + 3] = fmaf(a, wv.w, acc[4 * q + 3]);
            }
        }
        __syncthreads();
#pragma unroll
        for (int j = 0; j < 16; j++)
            sh[lane * 65 + cb + j] = fmaxf(acc[j], 0.f);
        __syncthreads();

        // ---- GEMM2 ----
#pragma unroll
        for (int j = 0; j < 16; j++) acc[j] = b2[cb + j];
        for (int k = 0; k < 64; k++) {
            float a = sh[lane * 65 + k];
            const float4* wr = (const float4*)(W2 + k * 64 + cb);
#pragma unroll
            for (int q = 0; q < 4; q++) {
                float4 wv = wr[q];
                acc[4 * q + 0] = fmaf(a, wv.x, acc[4 * q + 0]);
                acc[4 * q + 1] = fmaf(a, wv.y, acc[4 * q + 1]);
                acc[4 * q + 2] = fmaf(a, wv.z, acc[4 * q + 2]);
                acc[4 * q + 3] = fmaf(a, wv.w, acc[4 * q + 3]);
            }
        }
        __syncthreads();
#pragma unroll
        for (int j = 0; j < 16; j++)
            sh[lane * 65 + cb + j] = acc[j];
        __syncthreads();

        // ---- stores: fp32 + optional bf16 table ----
#pragma unroll
        for (int i = 0; i < 4; i++) {
            int i4 = tid + 256 * i;
            int row = i4 >> 4, col = (i4 & 15) * 4;
            int grow = base + row;
            if (grow < NN) {
                const float* s = sh + row * 65 + col;
                float4 v = make_float4(s[0], s[1], s[2], s[3]);
                *(float4*)(hout + (size_t)grow * HD + col) = v;
                if (WRITE_XB) {
                    union { ushort4 u; __hip_bfloat16 b[4]; } pk;
                    pk.b[0] = __float2bfloat16(v.x);
                    pk.b[1] = __float2bfloat16(v.y);
                    pk.b[2] = __float2bfloat16(v.z);
                    pk.b[3] = __float2bfloat16(v.w);
                    *(ushort4*)((unsigned short*)xbr + (size_t)grow * HD + col) = pk.u;
                }
            }
        }

        // ---- BN-stats partials: wave w sums rows [w*16, w*16+16) ----
        {
            float s = 0.f, ss = 0.f;
#pragma unroll
            for (int r = 0; r < 16; r++) {
                int rl = wu * 16 + r;
                float v = (base + rl < NN) ? sh[rl * 65 + lane] : 0.f;
                s += v;
                ss += v * v;
            }
            red[0][wu][lane] = s;
            red[1][wu][lane] = ss;
            __syncthreads();
            if (tid < 64) {
                float S = red[0][0][tid] + red[0][1][tid] + red[0][2][tid] + red[0][3][tid];
                atomicAdd(stats + tid, S);
            } else if (tid < 128) {
                int c = tid - 64;
                float SS = red[1][0][c] + red[1][1][c] + red[1][2][c] + red[1][3][c];
                atomicAdd(stats + 64 + c, SS);
            }
        }
    }
}

// ---------------------------------------------------------------------------
// The persistent mega-kernel (regular launch; residency = R21-measured).
// ---------------------------------------------------------------------------
__global__ __launch_bounds__(256, 6)
void gin_mega(const float* __restrict__ x, const int* __restrict__ ei,
              const int* __restrict__ batch,
              const float* __restrict__ W1_0, const float* __restrict__ b1_0,
              const float* __restrict__ W2_0, const float* __restrict__ b2_0,
              const float* __restrict__ g_0, const float* __restrict__ be_0,
              const float* __restrict__ W1_1, const float* __restrict__ b1_1,
              const float* __restrict__ W2_1, const float* __restrict__ b2_1,
              const float* __restrict__ g_1, const float* __restrict__ be_1,
              float* __restrict__ out, float* __restrict__ stats0,
              float* __restrict__ stats1, float* __restrict__ psums,
              int* __restrict__ cnt, unsigned short* __restrict__ csr,
              __hip_bfloat16* __restrict__ xb, __hip_bfloat16* __restrict__ xb2,
              float* __restrict__ bh, unsigned int* __restrict__ ctr) {
    __shared__ float sh[64 * 65];       // 16.6 KB
    __shared__ float red[2][4][64];     // 2 KB (reused as sg in norm)
    int tid = threadIdx.x;
    int bid = blockIdx.x;

    // ===== P1: XCD-partitioned scatter (partition = bid&7, GRID%8==0) =====
    for (int v = bid; v < SCTV; v += GRID) {
        int p = v & 7;
        int chunk = v >> 3;
        int e4 = (chunk * 256 + tid) * 4;
        if (e4 < NE) {
            int4 s = *(const int4*)(ei + e4);
            int4 d = *(const int4*)(ei + NE + e4);
            int lo = p * PSZ, hi = lo + PSZ;
            int slot;
            if (d.x >= lo && d.x < hi) {
                slot = atomicAdd(&cnt[d.x], 1);
                if (slot < ROWCAP) csr[(d.x << 6) + slot] = (unsigned short)s.x;
            }
            if (d.y >= lo && d.y < hi) {
                slot = atomicAdd(&cnt[d.y], 1);
                if (slot < ROWCAP) csr[(d.y << 6) + slot] = (unsigned short)s.y;
            }
            if (d.z >= lo && d.z < hi) {
                slot = atomicAdd(&cnt[d.z], 1);
                if (slot < ROWCAP) csr[(d.z << 6) + slot] = (unsigned short)s.z;
            }
            if (d.w >= lo && d.w < hi) {
                slot = atomicAdd(&cnt[d.w], 1);
                if (slot < ROWCAP) csr[(d.w << 6) + slot] = (unsigned short)s.w;
            }
        }
    }
    devbar(ctr, 1u * GRID);

    // ===== P2: layer-0 gather -> buf_h =====
    gather_phase<0>(x, xb, cnt, csr, nullptr, nullptr, nullptr, bh);
    devbar(ctr, 2u * GRID);

    // ===== P3: layer-0 MLP -> out (fp32) + xb2 (bf16) + stats0 =====
    mlp_phase<true>(bh, W1_0, b1_0, W2_0, b2_0, out, stats0, xb2, sh, red);
    devbar(ctr, 3u * GRID);

    // ===== P4: layer-1 gather (BN0+ReLU on the fly) -> buf_h =====
    gather_phase<1>(out, xb2, cnt, csr, stats0, g_0, be_0, bh);
    devbar(ctr, 4u * GRID);

    // ===== P5: layer-1 MLP -> out + stats1 =====
    mlp_phase<false>(bh, W1_1, b1_1, W2_1, b2_1, out, stats1,
                     (__hip_bfloat16*)nullptr, sh, red);
    devbar(ctr, 5u * GRID);

    // ===== P6: final BN + ReLU + pool partials =====
    {
        float* sg = &red[0][0][0];  // 128 floats
        for (int nb = bid; nb < NORMV; nb += GRID) {
            if (tid < 128) sg[tid] = 0.f;
            __syncthreads();
            size_t i4 = (size_t)nb * 256 + tid;
            int rrow = (int)(i4 >> 4);
            int base_row = nb * 16;
            int g0 = batch[base_row];
            size_t off = i4 * 4;
            int col = (int)(off & 63);
            float4 v = *(const float4*)(out + off);
            float4 sm = *(const float4*)(stats1 + col);
            float4 sq = *(const float4*)(stats1 + 64 + col);
            float4 gg = *(const float4*)(g_1 + col);
            float4 bb = *(const float4*)(be_1 + col);
            const float inv = 1.f / (float)NN;
            float4 o;
            {
                float mu = sm.x * inv, var = sq.x * inv - mu * mu;
                float s = gg.x * rsqrtf(var + BN_EPS);
                o.x = fmaxf((v.x - mu) * s + bb.x, 0.f);
            }
            {
                float mu = sm.y * inv, var = sq.y * inv - mu * mu;
                float s = gg.y * rsqrtf(var + BN_EPS);
                o.y = fmaxf((v.y - mu) * s + bb.y, 0.f);
            }
            {
                float mu = sm.z * inv, var = sq.z * inv - mu * mu;
                float s = gg.z * rsqrtf(var + BN_EPS);
                o.z = fmaxf((v.z - mu) * s + bb.z, 0.f);
            }
            {
                float mu = sm.w * inv, var = sq.w * inv - mu * mu;
                float s = gg.w * rsqrtf(var + BN_EPS);
                o.w = fmaxf((v.w - mu) * s + bb.w, 0.f);
            }
            *(float4*)(out + off) = o;

            int dg = batch[rrow] - g0;
            if (dg <= 1) {
                atomicAdd(&sg[dg * 64 + col + 0], o.x);
                atomicAdd(&sg[dg * 64 + col + 1], o.y);
                atomicAdd(&sg[dg * 64 + col + 2], o.z);
                atomicAdd(&sg[dg * 64 + col + 3], o.w);
            } else {
                int gid = g0 + dg;
                atomicAdd(&psums[gid * HD + col + 0], o.x);
                atomicAdd(&psums[gid * HD + col + 1], o.y);
                atomicAdd(&psums[gid * HD + col + 2], o.z);
                atomicAdd(&psums[gid * HD + col + 3], o.w);
            }
            __syncthreads();
            if (tid < 128) {
                int d = tid >> 6;
                int c = tid & 63;
                float s = sg[d * 64 + c];
                if (g0 + d < NG && s != 0.f) atomicAdd(&psums[(g0 + d) * HD + c], s);
            }
            __syncthreads();
        }
    }
    devbar(ctr, 6u * GRID);

    // ===== P7: pool finalize (block 0) =====
    if (bid == 0) {
        for (int idx = tid; idx < NG * HD; idx += TPB) {
            int g = idx >> 6;
            int col = idx & 63;
            int s = lower_bound_batch(batch, g);
            int e = lower_bound_batch(batch, g + 1);
            float c = (float)(e - s);
            out[(size_t)NN * HD + g * HD + col] = psums[g * HD + col] / fmaxf(c, 1.f);
        }
    }
}

extern "C" void kernel_launch(void* const* d_in, const int* in_sizes, int n_in,
                              void* d_out, int out_size, void* d_ws, size_t ws_size,
                              hipStream_t stream) {
    const float* x = (const float*)d_in[0];
    const int* ei = (const int*)d_in[1];
    const int* batch = (const int*)d_in[2];
    const float* W1_0 = (const float*)d_in[3];
    const float* b1_0 = (const float*)d_in[4];
    const float* W2_0 = (const float*)d_in[5];
    const float* b2_0 = (const float*)d_in[6];
    const float* g_0 = (const float*)d_in[7];
    const float* be_0 = (const float*)d_in[8];
    const float* W1_1 = (const float*)d_in[9];
    const float* b1_1 = (const float*)d_in[10];
    const float* W2_1 = (const float*)d_in[11];
    const float* b2_1 = (const float*)d_in[12];
    const float* g_1 = (const float*)d_in[13];
    const float* be_1 = (const float*)d_in[14];

    float* out = (float*)d_out;

    // workspace layout (~33 MB)
    float* stats0 = (float*)d_ws;                      // 128 f32
    float* stats1 = stats0 + 128;                      // 128 f32
    float* psums = stats1 + 128;                       // 1024 f32
    unsigned int* ctr = (unsigned int*)(psums + 1024); // 1 u32 (+pad to 16)
    int* cnt = (int*)(ctr + 16);                       // NN int
    unsigned short* csr = (unsigned short*)(cnt + NN); // NN*ROWCAP u16 (6.4 MB)
    __hip_bfloat16* xb = (__hip_bfloat16*)(csr + (size_t)NN * ROWCAP);   // bf16 x
    __hip_bfloat16* xb2 = xb + (size_t)NN * HD;        // bf16 raw L0 (separate!)
    float* bh = (float*)(xb2 + (size_t)NN * HD);       // NN*HD f32 agg buffer

    int prep_grid = (NN * HD / 4 + 255) / 256;         // 3125

    prep_kernel<<<prep_grid, dim3(256), 0, stream>>>(x, xb, cnt, stats0, stats1,
                                                     psums, ctr);
    gin_mega<<<GRID, dim3(TPB), 0, stream>>>(
        x, ei, batch,
        W1_0, b1_0, W2_0, b2_0, g_0, be_0,
        W1_1, b1_1, W2_1, b2_1, g_1, be_1,
        out, stats0, stats1, psums, cnt, csr, xb, xb2, bh, ctr);
}

// Round 9
// 273.356 us; speedup vs baseline: 11.5564x; 3.8890x over previous
//
#include <hip/hip_runtime.h>
#include <hip/hip_bf16.h>

// GIN: 2 x (padded-CSR gather-sum + MLP(64->64->64) + BatchNorm + ReLU) + mean pool
// N=50000 nodes, E=800000 edges, H=64, G=16 graphs. fp32 in/out.
// R23 = R16 (best known, 275.9us) + 4-rows-per-instruction gather:
//  - persistent/cooperative attempts (R21/R22) showed cross-XCD barriers cost
//    >=100us each on this chip; dispatch boundaries (~10us) are the cheap
//    grid-wide barrier. Split pipeline restored verbatim.
//  - agg/aggn inner loop: lane l loads uint2 (4 bf16 cols) of neighbor
//    j+(l>>4) -> one VMEM instruction covers 4 neighbor rows (512B) instead
//    of 1 (128B). 4x fewer VMEM instrs + shfls -> ~4x rows in flight for the
//    latency-bound gather. 2-stage shfl_xor butterfly merges the 4 groups.
// 8 dispatches: prep, scatter, agg, mlp, aggn, mlp, norm, finalize.

constexpr int NN = 50000;
constexpr int NE = 800000;
constexpr int HD = 64;
constexpr int NG = 16;
constexpr float BN_EPS = 1e-5f;
constexpr int ROWCAP = 64;   // max degree capacity; P(deg>64)~1e-20 at E/N=16
constexpr int NPART = 8;     // XCD partitions
constexpr int PSZ = 6250;    // rows per partition
constexpr int PBLK = (PSZ + 3) / 4;  // 1563 agg blocks per partition

// ---------------------------------------------------------------------------
// Prep: fp32 -> bf16 table conversion; zero cnt[], stats0/1, psums.
// ---------------------------------------------------------------------------
__global__ __launch_bounds__(256)
void prep_kernel(const float* __restrict__ x, __hip_bfloat16* __restrict__ xb,
                 int* __restrict__ cnt, float* __restrict__ stats0,
                 float* __restrict__ stats1, float* __restrict__ psums) {
    int i4 = blockIdx.x * 256 + threadIdx.x;
    if (i4 < NN) cnt[i4] = 0;
    if (blockIdx.x == 0) {
        if (threadIdx.x < 128) stats0[threadIdx.x] = 0.f;
        else stats1[threadIdx.x - 128] = 0.f;
    } else if (blockIdx.x == 1) {
        *(float4*)(psums + threadIdx.x * 4) = make_float4(0.f, 0.f, 0.f, 0.f);
    }
    if (i4 >= NN * HD / 4) return;
    float4 v = *(const float4*)(x + (size_t)i4 * 4);
    union { ushort4 u; __hip_bfloat16 b[4]; } p;
    p.b[0] = __float2bfloat16(v.x);
    p.b[1] = __float2bfloat16(v.y);
    p.b[2] = __float2bfloat16(v.z);
    p.b[3] = __float2bfloat16(v.w);
    *(ushort4*)((unsigned short*)xb + (size_t)i4 * 4) = p.u;
}

// ---------------------------------------------------------------------------
// XCD-partitioned scatter into degree-padded ushort CSR (R16, unchanged).
// Block b: partition b&7 (round-robin blockIdx->XCD), edge chunk b>>3.
// ---------------------------------------------------------------------------
__global__ __launch_bounds__(256)
void scatter_kernel(const int* __restrict__ ei, int* __restrict__ cnt,
                    unsigned short* __restrict__ csr) {
    int p = blockIdx.x & 7;
    int chunk = blockIdx.x >> 3;
    int e4 = (chunk * 256 + threadIdx.x) * 4;
    if (e4 >= NE) return;
    int4 s = *(const int4*)(ei + e4);
    int4 d = *(const int4*)(ei + NE + e4);
    int lo = p * PSZ, hi = lo + PSZ;
    int slot;
    if (d.x >= lo && d.x < hi) {
        slot = atomicAdd(&cnt[d.x], 1);
        if (slot < ROWCAP) csr[(d.x << 6) + slot] = (unsigned short)s.x;
    }
    if (d.y >= lo && d.y < hi) {
        slot = atomicAdd(&cnt[d.y], 1);
        if (slot < ROWCAP) csr[(d.y << 6) + slot] = (unsigned short)s.y;
    }
    if (d.z >= lo && d.z < hi) {
        slot = atomicAdd(&cnt[d.z], 1);
        if (slot < ROWCAP) csr[(d.z << 6) + slot] = (unsigned short)s.z;
    }
    if (d.w >= lo && d.w < hi) {
        slot = atomicAdd(&cnt[d.w], 1);
        if (slot < ROWCAP) csr[(d.w << 6) + slot] = (unsigned short)s.w;
    }
}

// ---------------------------------------------------------------------------
// Aggregation, 4-rows-per-instruction. One wave per dst row (R16 partition
// mapping: same XCD that scattered the row's CSR lines reads them back).
// lane l: group g=l>>4 handles neighbors j+g; slot s=l&15 covers columns
// 4s..4s+3 (uint2 = 4 bf16). Butterfly shfl_xor(16,32) merges groups.
// MODE 0: raw. MODE 1: apply prev-layer BN+ReLU per gathered value.
// ---------------------------------------------------------------------------
template <int MODE>
__global__ __launch_bounds__(256)
void agg_kernel(const float* __restrict__ xin, const __hip_bfloat16* __restrict__ xg,
                const int* __restrict__ cnt, const unsigned short* __restrict__ csr,
                const float* __restrict__ stats_prev, const float* __restrict__ gp,
                const float* __restrict__ bep, float* __restrict__ h) {
    int lr = ((blockIdx.x >> 3) << 2) + (threadIdx.x >> 6);
    if (lr >= PSZ) return;
    int row = (blockIdx.x & 7) * PSZ + lr;
    int lane = threadIdx.x & 63;
    int s4 = (lane & 15) * 4;   // column base for this lane
    int g = lane >> 4;          // neighbor group 0..3

    float4 sc4 = make_float4(1.f, 1.f, 1.f, 1.f);
    float4 off4 = make_float4(0.f, 0.f, 0.f, 0.f);
    if (MODE == 1) {
        const float inv = 1.f / (float)NN;
        float4 sm = *(const float4*)(stats_prev + s4);
        float4 sq = *(const float4*)(stats_prev + 64 + s4);
        float4 gg = *(const float4*)(gp + s4);
        float4 bb = *(const float4*)(bep + s4);
        float mu, var;
        mu = sm.x * inv; var = sq.x * inv - mu * mu;
        sc4.x = gg.x * rsqrtf(var + BN_EPS); off4.x = bb.x - mu * sc4.x;
        mu = sm.y * inv; var = sq.y * inv - mu * mu;
        sc4.y = gg.y * rsqrtf(var + BN_EPS); off4.y = bb.y - mu * sc4.y;
        mu = sm.z * inv; var = sq.z * inv - mu * mu;
        sc4.z = gg.z * rsqrtf(var + BN_EPS); off4.z = bb.z - mu * sc4.z;
        mu = sm.w * inv; var = sq.w * inv - mu * mu;
        sc4.w = gg.w * rsqrtf(var + BN_EPS); off4.w = bb.w - mu * sc4.w;
    }

    int m = min(cnt[row], ROWCAP);
    int ids = (int)csr[((size_t)row << 6) + lane];
    const unsigned short* xgp = (const unsigned short*)xg;

    float4 accA = make_float4(0.f, 0.f, 0.f, 0.f);
    float4 accB = make_float4(0.f, 0.f, 0.f, 0.f);
    if (g == 0) {  // self term added by group 0 only
        float4 sv = *(const float4*)(xin + (size_t)row * HD + s4);
        if (MODE == 1) {
            accA.x = fmaxf(fmaf(sv.x, sc4.x, off4.x), 0.f);
            accA.y = fmaxf(fmaf(sv.y, sc4.y, off4.y), 0.f);
            accA.z = fmaxf(fmaf(sv.z, sc4.z, off4.z), 0.f);
            accA.w = fmaxf(fmaf(sv.w, sc4.w, off4.w), 0.f);
        } else {
            accA = sv;
        }
    }

#define ACC_U2(ACC, U)                                                        \
    {                                                                         \
        float v0 = __uint_as_float((U).x << 16);                              \
        float v1 = __uint_as_float((U).x & 0xffff0000u);                      \
        float v2 = __uint_as_float((U).y << 16);                              \
        float v3 = __uint_as_float((U).y & 0xffff0000u);                      \
        if (MODE == 1) {                                                      \
            ACC.x += fmaxf(fmaf(v0, sc4.x, off4.x), 0.f);                     \
            ACC.y += fmaxf(fmaf(v1, sc4.y, off4.y), 0.f);                     \
            ACC.z += fmaxf(fmaf(v2, sc4.z, off4.z), 0.f);                     \
            ACC.w += fmaxf(fmaf(v3, sc4.w, off4.w), 0.f);                     \
        } else {                                                              \
            ACC.x += v0; ACC.y += v1; ACC.z += v2; ACC.w += v3;               \
        }                                                                     \
    }

    int j = 0;
    for (; j + 8 <= m; j += 8) {  // 8 neighbors per iter: 2 loads/lane
        int nb0 = __shfl(ids, j + g);
        int nb1 = __shfl(ids, j + 4 + g);
        uint2 u0 = *(const uint2*)(xgp + ((size_t)nb0 << 6) + s4);
        uint2 u1 = *(const uint2*)(xgp + ((size_t)nb1 << 6) + s4);
        ACC_U2(accA, u0);
        ACC_U2(accB, u1);
    }
    for (; j < m; j += 4) {  // tail: up to 4 neighbors, predicated by group
        int nb = __shfl(ids, j + g);  // j wave-uniform; shfl unconditional
        if (j + g < m) {
            uint2 u = *(const uint2*)(xgp + ((size_t)nb << 6) + s4);
            ACC_U2(accA, u);
        }
    }
#undef ACC_U2

    float4 acc = make_float4(accA.x + accB.x, accA.y + accB.y,
                             accA.z + accB.z, accA.w + accB.w);
    // butterfly across the 4 groups (lanes xor 16, 32)
    acc.x += __shfl_xor(acc.x, 16);
    acc.y += __shfl_xor(acc.y, 16);
    acc.z += __shfl_xor(acc.z, 16);
    acc.w += __shfl_xor(acc.w, 16);
    acc.x += __shfl_xor(acc.x, 32);
    acc.y += __shfl_xor(acc.y, 32);
    acc.z += __shfl_xor(acc.z, 32);
    acc.w += __shfl_xor(acc.w, 32);

    if (g == 0)
        *(float4*)(h + (size_t)row * HD + s4) = acc;
}

// ---------------------------------------------------------------------------
// Fused MLP + BN-stats epilogue (R16, unchanged). Optional bf16 dual-write.
// ---------------------------------------------------------------------------
__global__ __launch_bounds__(256)
void mlp_kernel(const float* __restrict__ hin, float* __restrict__ hout,
                const float* __restrict__ W1, const float* __restrict__ b1,
                const float* __restrict__ W2, const float* __restrict__ b2,
                float* __restrict__ stats, __hip_bfloat16* __restrict__ xbr) {
    __shared__ float sh[128 * 65];
    __shared__ float sW[64 * 64];
    __shared__ float sb[64];
    __shared__ float red[2][4][64];
    int tid = threadIdx.x;
    int base = blockIdx.x * 128;

    for (int i = tid; i < 4096; i += 256) sW[i] = W1[i];
    if (tid < 64) sb[tid] = b1[tid];
#pragma unroll
    for (int i = 0; i < 8; i++) {
        int i4 = tid + 256 * i;
        int row = i4 >> 4, col = (i4 & 15) * 4;
        int grow = base + row;
        float4 v = (grow < NN) ? *(const float4*)(hin + (size_t)grow * HD + col)
                               : make_float4(0.f, 0.f, 0.f, 0.f);
        float* d = sh + row * 65 + col;
        d[0] = v.x; d[1] = v.y; d[2] = v.z; d[3] = v.w;
    }
    __syncthreads();

    int wv = tid >> 6;
    int lane = tid & 63;

    float acc0[16], acc1[16];
    // ---- GEMM1 ----
#pragma unroll
    for (int j = 0; j < 16; j++) { acc0[j] = sb[wv * 16 + j]; acc1[j] = acc0[j]; }
    for (int k = 0; k < 64; k++) {
        float a0 = sh[lane * 65 + k];
        float a1 = sh[(64 + lane) * 65 + k];
        const float4* wr = (const float4*)(sW + k * 64 + wv * 16);
#pragma unroll
        for (int q = 0; q < 4; q++) {
            float4 w = wr[q];
            acc0[4 * q + 0] = fmaf(a0, w.x, acc0[4 * q + 0]);
            acc0[4 * q + 1] = fmaf(a0, w.y, acc0[4 * q + 1]);
            acc0[4 * q + 2] = fmaf(a0, w.z, acc0[4 * q + 2]);
            acc0[4 * q + 3] = fmaf(a0, w.w, acc0[4 * q + 3]);
            acc1[4 * q + 0] = fmaf(a1, w.x, acc1[4 * q + 0]);
            acc1[4 * q + 1] = fmaf(a1, w.y, acc1[4 * q + 1]);
            acc1[4 * q + 2] = fmaf(a1, w.z, acc1[4 * q + 2]);
            acc1[4 * q + 3] = fmaf(a1, w.w, acc1[4 * q + 3]);
        }
    }
    __syncthreads();

    // t = ReLU(acc) overwrites sh; restage W2/b2
#pragma unroll
    for (int j = 0; j < 16; j++) {
        sh[lane * 65 + wv * 16 + j] = fmaxf(acc0[j], 0.f);
        sh[(64 + lane) * 65 + wv * 16 + j] = fmaxf(acc1[j], 0.f);
    }
    for (int i = tid; i < 4096; i += 256) sW[i] = W2[i];
    if (tid < 64) sb[tid] = b2[tid];
    __syncthreads();

    // ---- GEMM2 ----
#pragma unroll
    for (int j = 0; j < 16; j++) { acc0[j] = sb[wv * 16 + j]; acc1[j] = acc0[j]; }
    for (int k = 0; k < 64; k++) {
        float a0 = sh[lane * 65 + k];
        float a1 = sh[(64 + lane) * 65 + k];
        const float4* wr = (const float4*)(sW + k * 64 + wv * 16);
#pragma unroll
        for (int q = 0; q < 4; q++) {
            float4 w = wr[q];
            acc0[4 * q + 0] = fmaf(a0, w.x, acc0[4 * q + 0]);
            acc0[4 * q + 1] = fmaf(a0, w.y, acc0[4 * q + 1]);
            acc0[4 * q + 2] = fmaf(a0, w.z, acc0[4 * q + 2]);
            acc0[4 * q + 3] = fmaf(a0, w.w, acc0[4 * q + 3]);
            acc1[4 * q + 0] = fmaf(a1, w.x, acc1[4 * q + 0]);
            acc1[4 * q + 1] = fmaf(a1, w.y, acc1[4 * q + 1]);
            acc1[4 * q + 2] = fmaf(a1, w.z, acc1[4 * q + 2]);
            acc1[4 * q + 3] = fmaf(a1, w.w, acc1[4 * q + 3]);
        }
    }
    __syncthreads();
#pragma unroll
    for (int j = 0; j < 16; j++) {
        sh[lane * 65 + wv * 16 + j] = acc0[j];
        sh[(64 + lane) * 65 + wv * 16 + j] = acc1[j];
    }
    __syncthreads();

    // coalesced stores: fp32 always; bf16 raw table if requested
#pragma unroll
    for (int i = 0; i < 8; i++) {
        int i4 = tid + 256 * i;
        int row = i4 >> 4, col = (i4 & 15) * 4;
        int grow = base + row;
        if (grow < NN) {
            const float* s = sh + row * 65 + col;
            float4 v = make_float4(s[0], s[1], s[2], s[3]);
            *(float4*)(hout + (size_t)grow * HD + col) = v;
            if (xbr) {
                union { ushort4 u; __hip_bfloat16 b[4]; } p;
                p.b[0] = __float2bfloat16(v.x);
                p.b[1] = __float2bfloat16(v.y);
                p.b[2] = __float2bfloat16(v.z);
                p.b[3] = __float2bfloat16(v.w);
                *(ushort4*)((unsigned short*)xbr + (size_t)grow * HD + col) = p.u;
            }
        }
    }

    // ---- fused BN-stats partials ----
    {
        int col = tid & 63;
        int r0 = (tid >> 6) * 32;
        float s = 0.f, ss = 0.f;
#pragma unroll
        for (int r = 0; r < 32; r++) {
            float v = (base + r0 + r < NN) ? sh[(r0 + r) * 65 + col] : 0.f;
            s += v;
            ss += v * v;
        }
        red[0][tid >> 6][col] = s;
        red[1][tid >> 6][col] = ss;
        __syncthreads();
        if (tid < 64) {
            float S = red[0][0][col] + red[0][1][col] + red[0][2][col] + red[0][3][col];
            atomicAdd(stats + col, S);
        } else if (tid < 128) {
            float SS = red[1][0][col] + red[1][1][col] + red[1][2][col] + red[1][3][col];
            atomicAdd(stats + 64 + col, SS);
        }
    }
}

// ---------------------------------------------------------------------------
// Final BatchNorm + affine + ReLU with fused mean-pool partials (R16).
// ---------------------------------------------------------------------------
__global__ __launch_bounds__(256)
void norm_kernel(float* h, const float* __restrict__ stats,
                 const float* __restrict__ g, const float* __restrict__ be,
                 const int* __restrict__ batch, float* __restrict__ psums) {
    __shared__ float sg[2][64];
    if (threadIdx.x < 128) sg[threadIdx.x >> 6][threadIdx.x & 63] = 0.f;
    __syncthreads();
    size_t i4 = (size_t)blockIdx.x * 256 + threadIdx.x;
    int row = (int)(i4 >> 4);            // 16 threads (4 cols each) per row
    int base_row = blockIdx.x * 16;
    int g0 = batch[base_row];
    size_t off = i4 * 4;
    int col = (int)(off & 63);
    float4 v = *(const float4*)(h + off);
    float4 sm = *(const float4*)(stats + col);
    float4 sq = *(const float4*)(stats + 64 + col);
    float4 gg = *(const float4*)(g + col);
    float4 bb = *(const float4*)(be + col);
    const float inv = 1.f / (float)NN;
    float4 o;
    {
        float mu = sm.x * inv, var = sq.x * inv - mu * mu;
        float sc = gg.x * rsqrtf(var + BN_EPS);
        o.x = fmaxf((v.x - mu) * sc + bb.x, 0.f);
    }
    {
        float mu = sm.y * inv, var = sq.y * inv - mu * mu;
        float sc = gg.y * rsqrtf(var + BN_EPS);
        o.y = fmaxf((v.y - mu) * sc + bb.y, 0.f);
    }
    {
        float mu = sm.z * inv, var = sq.z * inv - mu * mu;
        float sc = gg.z * rsqrtf(var + BN_EPS);
        o.z = fmaxf((v.z - mu) * sc + bb.z, 0.f);
    }
    {
        float mu = sm.w * inv, var = sq.w * inv - mu * mu;
        float sc = gg.w * rsqrtf(var + BN_EPS);
        o.w = fmaxf((v.w - mu) * sc + bb.w, 0.f);
    }
    *(float4*)(h + off) = o;

    // pool partials
    int dg = batch[row] - g0;
    if (dg <= 1) {
        atomicAdd(&sg[dg][col + 0], o.x);
        atomicAdd(&sg[dg][col + 1], o.y);
        atomicAdd(&sg[dg][col + 2], o.z);
        atomicAdd(&sg[dg][col + 3], o.w);
    } else {  // >2 graphs in one 16-row window (never at ~3125 rows/graph)
        int gid = g0 + dg;
        atomicAdd(&psums[gid * HD + col + 0], o.x);
        atomicAdd(&psums[gid * HD + col + 1], o.y);
        atomicAdd(&psums[gid * HD + col + 2], o.z);
        atomicAdd(&psums[gid * HD + col + 3], o.w);
    }
    __syncthreads();
    if (threadIdx.x < 128) {
        int d = threadIdx.x >> 6;
        int c = threadIdx.x & 63;
        float s = sg[d][c];
        if (g0 + d < NG && s != 0.f) atomicAdd(&psums[(g0 + d) * HD + c], s);
    }
}

// ---------------------------------------------------------------------------
// Pool finalize (R16, unchanged).
// ---------------------------------------------------------------------------
__device__ __forceinline__ int lower_bound_batch(const int* __restrict__ b, int val) {
    int lo = 0, hi = NN;
    while (lo < hi) {
        int mid = (lo + hi) >> 1;
        if (b[mid] < val) lo = mid + 1;
        else hi = mid;
    }
    return lo;
}

__global__ __launch_bounds__(1024)
void pool_finalize_kernel(const float* __restrict__ sums, const int* __restrict__ batch,
                          float* __restrict__ out) {
    int g = threadIdx.x >> 6;
    int col = threadIdx.x & 63;
    int s = lower_bound_batch(batch, g);
    int e = lower_bound_batch(batch, g + 1);
    float cnt = (float)(e - s);
    out[g * HD + col] = sums[g * HD + col] / fmaxf(cnt, 1.f);
}

extern "C" void kernel_launch(void* const* d_in, const int* in_sizes, int n_in,
                              void* d_out, int out_size, void* d_ws, size_t ws_size,
                              hipStream_t stream) {
    const float* x = (const float*)d_in[0];
    const int* ei = (const int*)d_in[1];
    const int* batch = (const int*)d_in[2];
    const float* W1_0 = (const float*)d_in[3];
    const float* b1_0 = (const float*)d_in[4];
    const float* W2_0 = (const float*)d_in[5];
    const float* b2_0 = (const float*)d_in[6];
    const float* g_0 = (const float*)d_in[7];
    const float* be_0 = (const float*)d_in[8];
    const float* W1_1 = (const float*)d_in[9];
    const float* b1_1 = (const float*)d_in[10];
    const float* W2_1 = (const float*)d_in[11];
    const float* b2_1 = (const float*)d_in[12];
    const float* g_1 = (const float*)d_in[13];
    const float* be_1 = (const float*)d_in[14];

    float* out = (float*)d_out;  // raw L0 h2 -> raw L1 h2 -> final normalized

    // workspace layout (~26 MB)
    float* buf_h = (float*)d_ws;                       // NN*HD f32 (12.8 MB)
    float* stats0 = buf_h + (size_t)NN * HD;           // 128 f32
    float* stats1 = stats0 + 128;                      // 128 f32
    float* psums = stats1 + 128;                       // 1024 f32
    int* cnt = (int*)(psums + 1024);                   // NN int
    unsigned short* csr = (unsigned short*)(cnt + NN); // NN*ROWCAP u16 (6.4 MB)
    __hip_bfloat16* xb = (__hip_bfloat16*)(csr + (size_t)NN * ROWCAP);  // NN*HD bf16

    dim3 b256(256);
    int mlp_grid = (NN + 127) / 128;              // 391
    int norm_grid = (NN * HD / 4 + 255) / 256;    // 3125
    int sct_grid = ((NE + 1023) / 1024) * NPART;  // 782 chunks x 8 = 6256
    int agg_grid = NPART * PBLK;                  // 8 x 1563 = 12504

    // ---- padded-CSR build (2 dispatches) ----
    prep_kernel<<<norm_grid, b256, 0, stream>>>(x, xb, cnt, stats0, stats1, psums);
    scatter_kernel<<<sct_grid, b256, 0, stream>>>(ei, cnt, csr);

    // ---- layer 0 ----
    agg_kernel<0><<<agg_grid, b256, 0, stream>>>(x, xb, cnt, csr,
                                                 nullptr, nullptr, nullptr, buf_h);
    // mlp writes raw-L0 bf16 back into xb: safe under dispatch boundaries
    // (agg has fully consumed xb before mlp starts).
    mlp_kernel<<<mlp_grid, b256, 0, stream>>>(buf_h, out, W1_0, b1_0, W2_0, b2_0,
                                              stats0, xb);

    // ---- layer 1 (agg applies layer-0 BN+ReLU on the fly) ----
    agg_kernel<1><<<agg_grid, b256, 0, stream>>>(out, xb, cnt, csr,
                                                 stats0, g_0, be_0, buf_h);
    mlp_kernel<<<mlp_grid, b256, 0, stream>>>(buf_h, out, W1_1, b1_1, W2_1, b2_1,
                                              stats1, (__hip_bfloat16*)nullptr);

    // ---- final norm + fused pool partials, then tiny finalize ----
    norm_kernel<<<norm_grid, b256, 0, stream>>>(out, stats1, g_1, be_1, batch, psums);
    pool_finalize_kernel<<<1, dim3(1024), 0, stream>>>(psums, batch, out + (size_t)NN * HD);
}